// Round 3
// baseline (1174.857 us; speedup 1.0000x reference)
//
#include <hip/hip_runtime.h>
#include <hip/hip_fp16.h>

// NodeModel: edge MLP (Lin->BN->ReLU->Lin) -> scatter_add -> node MLP (same).
// f16 MFMA 16x16x32, fp32 accumulate. Two-pass BN (stats then apply+GEMM2).
// R5: counting-sort edges by dest col; segmented-scan collapses equal-col runs
//     so only run tails issue pk-f16 atomics (WRITE 200->24 MB, 353->183 us).
// R6: BARRIER-FREE edge loops. Each wave loads its OWN 16 rows' A-fragments
//     directly global->reg (lane (lm,q) reads row wv*16+lm, k-slice q*8),
//     so no input staging LDS, no double buffer, no in-loop __syncthreads.
//     LDS = weights (+ wave-private transpose scratch). Waves self-pipeline
//     across tiles; atomics fire-and-forget. edge_stats LDS drops to 35 KB.

typedef _Float16 half8  __attribute__((ext_vector_type(8)));
typedef _Float16 half4h __attribute__((ext_vector_type(4)));
typedef float    floatx4 __attribute__((ext_vector_type(4)));

#define MFMA16(a, b, c) __builtin_amdgcn_mfma_f32_16x16x32_f16(a, b, c, 0, 0, 0)

#define CVT8(lo, hi) (half8){(_Float16)(lo)[0], (_Float16)(lo)[1], (_Float16)(lo)[2], (_Float16)(lo)[3], \
                             (_Float16)(hi)[0], (_Float16)(hi)[1], (_Float16)(hi)[2], (_Float16)(hi)[3]}

__device__ __forceinline__ float col_reduce16(float v) {
    v += __shfl_xor(v, 16, 64);
    v += __shfl_xor(v, 32, 64);
    return v;
}

// ---------------------------------------------------------------- k_prep ----
__global__ void k_prep(const float* __restrict__ w1a, const float* __restrict__ w2a,
                       const float* __restrict__ w1b, const float* __restrict__ w2b,
                       _Float16* __restrict__ w1at, _Float16* __restrict__ w2at,
                       _Float16* __restrict__ w1bt, _Float16* __restrict__ w2bt) {
    int i = blockIdx.x * 256 + threadIdx.x;           // 65536 total
    if (i < 16384) {
        int n = i >> 7, k = i & 127;
        w1at[n * 128 + k] = (_Float16)w1a[k * 128 + n];
    } else if (i < 32768) {
        int j = i - 16384; int n = j >> 7, k = j & 127;
        w2at[n * 128 + k] = (_Float16)w2a[k * 128 + n];
    } else if (i < 57344) {
        int j = i - 32768; int n = j / 192, k = j - n * 192;
        w1bt[n * 192 + k] = (_Float16)w1b[k * 128 + n];
    } else if (i < 65536) {
        int j = i - 57344; int n = j >> 7, k = j & 127;
        w2bt[n * 128 + k] = (_Float16)w2b[k * 64 + n];
    }
}

// ----------------------------------------------------------- sort kernels ---
__global__ void k_hist(const int* __restrict__ coli, int* __restrict__ cnt, int E) {
    int i = blockIdx.x * 512 + threadIdx.x;
    if (i < E) atomicAdd(&cnt[coli[i]], 1);
}

__global__ __launch_bounds__(1024) void k_scan(const int* __restrict__ cnt,
                                               int* __restrict__ cur, int N) {
    __shared__ int sp[1024];
    int t = threadIdx.x;
    int chunk = (N + 1023) >> 10;
    int base = t * chunk;
    int s = 0;
    for (int j = 0; j < chunk; j++) {
        int idx = base + j;
        if (idx < N) s += cnt[idx];
    }
    sp[t] = s; __syncthreads();
    for (int off = 1; off < 1024; off <<= 1) {
        int v = (t >= off) ? sp[t - off] : 0;
        __syncthreads();
        sp[t] += v;
        __syncthreads();
    }
    int run = sp[t] - s;          // exclusive prefix at chunk start
    for (int j = 0; j < chunk; j++) {
        int idx = base + j;
        if (idx < N) { cur[idx] = run; run += cnt[idx]; }
    }
}

__global__ void k_scatter(const int* __restrict__ rowi, const int* __restrict__ coli,
                          int* __restrict__ cur, int* __restrict__ rowp,
                          int* __restrict__ eidp, int* __restrict__ colp, int E) {
    int i = blockIdx.x * 512 + threadIdx.x;
    if (i < E) {
        int c = coli[i];
        int p = atomicAdd(&cur[c], 1);
        rowp[p] = rowi[i];
        eidp[p] = i;
        colp[p] = c;
    }
}

// ---------------------------------------------------------- k_edge_stats ----
// Pass 1: h1 = concat(x[row],ea) @ W1a; per-lane direct-from-global A-frags
// (lane (lm,q) owns tile-row wv*16+lm, k-slice q*8). No staging LDS, no
// in-loop barriers. Original edge order (ea streams).
__global__ __launch_bounds__(512, 4) void k_edge_stats(
    const float* __restrict__ x, const int* __restrict__ rowi,
    const float* __restrict__ ea, const _Float16* __restrict__ w1t,
    float* __restrict__ gsum, float* __restrict__ gsq, int nTiles) {
    __shared__ _Float16 sW[128][136];
    const int tid = threadIdx.x, lane = tid & 63, wv = tid >> 6;
    const int lm = lane & 15, q = lane >> 4, koff = q * 8;
    const int G = gridDim.x;
    const int row = wv * 16 + lm;       // A-frag row this lane feeds

    {   // stage W1^T once
        int n = tid >> 2, seg = (tid & 3) * 32;
        const half8* src = (const half8*)(w1t + n * 128 + seg);
        half8* dst = (half8*)&sW[n][seg];
        dst[0] = src[0]; dst[1] = src[1]; dst[2] = src[2]; dst[3] = src[3];
    }
    __syncthreads();

    float sAcc[8], ssAcc[8];
#pragma unroll
    for (int i = 0; i < 8; i++) { sAcc[i] = 0.f; ssAcc[i] = 0.f; }

    int t = blockIdx.x;
    floatx4 pv[8];
    {   // prologue: load tile t A-frags for this lane
        long ge = (long)t * 128 + row;
        const float* px = x + (long)rowi[ge] * 64 + koff;
        const float* pe = ea + ge * 64 + koff;
        pv[0] = *(const floatx4*)(px);      pv[1] = *(const floatx4*)(px + 4);
        pv[2] = *(const floatx4*)(px + 32); pv[3] = *(const floatx4*)(px + 36);
        pv[4] = *(const floatx4*)(pe);      pv[5] = *(const floatx4*)(pe + 4);
        pv[6] = *(const floatx4*)(pe + 32); pv[7] = *(const floatx4*)(pe + 36);
    }
    for (; t < nTiles; t += G) {
        half8 a[4];
        a[0] = CVT8(pv[0], pv[1]); a[1] = CVT8(pv[2], pv[3]);
        a[2] = CVT8(pv[4], pv[5]); a[3] = CVT8(pv[6], pv[7]);
        int tn = t + G;
        if (tn < nTiles) {   // prefetch next tile (overlaps GEMM1)
            long ge = (long)tn * 128 + row;
            const float* px = x + (long)rowi[ge] * 64 + koff;
            const float* pe = ea + ge * 64 + koff;
            pv[0] = *(const floatx4*)(px);      pv[1] = *(const floatx4*)(px + 4);
            pv[2] = *(const floatx4*)(px + 32); pv[3] = *(const floatx4*)(px + 36);
            pv[4] = *(const floatx4*)(pe);      pv[5] = *(const floatx4*)(pe + 4);
            pv[6] = *(const floatx4*)(pe + 32); pv[7] = *(const floatx4*)(pe + 36);
        }
#pragma unroll
        for (int nt = 0; nt < 8; nt++) {
            floatx4 acc = {0.f, 0.f, 0.f, 0.f};
            const int c = nt * 16 + lm;
#pragma unroll
            for (int kb = 0; kb < 4; kb++) {
                half8 b = *(const half8*)&sW[c][kb * 32 + koff];
                acc = MFMA16(a[kb], b, acc);
            }
            sAcc[nt]  += acc[0] + acc[1] + acc[2] + acc[3];
            ssAcc[nt] += acc[0]*acc[0] + acc[1]*acc[1] + acc[2]*acc[2] + acc[3]*acc[3];
        }
    }
#pragma unroll
    for (int nt = 0; nt < 8; nt++) {
        float s  = col_reduce16(sAcc[nt]);
        float ss = col_reduce16(ssAcc[nt]);
        if (q == 0) {
            int c = nt * 16 + lm;
            int slot = (blockIdx.x * 8 + wv) & 15;
            unsafeAtomicAdd(&gsum[slot * 128 + c], s);
            unsafeAtomicAdd(&gsq[slot * 128 + c], ss);
        }
    }
}

// ------------------------------------------------------------ k_finalize ----
__global__ void k_finalize(const float* __restrict__ sums, const float* __restrict__ sqs,
                           const float* __restrict__ gamma, const float* __restrict__ beta,
                           float* __restrict__ scale, float* __restrict__ shift, float count) {
    int i = threadIdx.x;   // 128
    float s = 0.f, ssq = 0.f;
    for (int j = 0; j < 16; j++) { s += sums[j * 128 + i]; ssq += sqs[j * 128 + i]; }
    float mu = s / count;
    float var = ssq / count - mu * mu;      // biased, matches torch/jax ref
    float sc = gamma[i] * rsqrtf(var + 1e-5f);
    scale[i] = sc;
    shift[i] = beta[i] - mu * sc;
}

// ------------------------------------------------------------ k_edge_mlp ----
// Pass 2 on SORTED edges, BARRIER-FREE: direct-from-global A-frags, GEMM1,
// BN+ReLU, wave-private LDS transpose, GEMM2(+b2a), segmented-scan scatter
// with tail-only pk-f16 atomics. Waves fully independent after weight stage.
__global__ __launch_bounds__(512, 2) void k_edge_mlp(
    const float* __restrict__ x, const int* __restrict__ rowp, const int* __restrict__ eidp,
    const int* __restrict__ colp,
    const float* __restrict__ ea, const _Float16* __restrict__ w1t, const _Float16* __restrict__ w2t,
    const float* __restrict__ scale, const float* __restrict__ shift, const float* __restrict__ b2a,
    __half* __restrict__ agg, int nTiles) {
    __shared__ _Float16 sW1[128][136];
    __shared__ _Float16 sW2[128][136];
    __shared__ _Float16 sT[128][136];   // h_bn transposed; per-wave column block
    __shared__ float sScale[128], sShift[128], sB2[128];
    const int tid = threadIdx.x, lane = tid & 63, wv = tid >> 6;
    const int lm = lane & 15, q = lane >> 4, koff = q * 8;
    const int G = gridDim.x;
    const int row = wv * 16 + lm;       // A-frag row
    const int m0 = wv * 16 + q * 4;     // D-frag rows m0..m0+3

    {   // stage both weight matrices once
        int n = tid >> 2, seg = (tid & 3) * 32;
        const half8* s1 = (const half8*)(w1t + n * 128 + seg);
        half8* d1 = (half8*)&sW1[n][seg];
        d1[0] = s1[0]; d1[1] = s1[1]; d1[2] = s1[2]; d1[3] = s1[3];
        const half8* s2 = (const half8*)(w2t + n * 128 + seg);
        half8* d2 = (half8*)&sW2[n][seg];
        d2[0] = s2[0]; d2[1] = s2[1]; d2[2] = s2[2]; d2[3] = s2[3];
    }
    if (tid < 128) { sScale[tid] = scale[tid]; sShift[tid] = shift[tid]; sB2[tid] = b2a[tid]; }
    __syncthreads();   // the only block-wide barrier

    int t = blockIdx.x;
    floatx4 pv[8]; int4 pcol;
    {   // prologue: tile t A-frags + dest cols
        long ge = (long)t * 128 + row;
        const float* px = x + (long)rowp[ge] * 64 + koff;
        const float* pe = ea + (long)eidp[ge] * 64 + koff;
        pv[0] = *(const floatx4*)(px);      pv[1] = *(const floatx4*)(px + 4);
        pv[2] = *(const floatx4*)(px + 32); pv[3] = *(const floatx4*)(px + 36);
        pv[4] = *(const floatx4*)(pe);      pv[5] = *(const floatx4*)(pe + 4);
        pv[6] = *(const floatx4*)(pe + 32); pv[7] = *(const floatx4*)(pe + 36);
        pcol = *(const int4*)&colp[(long)t * 128 + m0];
    }
    for (; t < nTiles; t += G) {
        half8 a[4];
        a[0] = CVT8(pv[0], pv[1]); a[1] = CVT8(pv[2], pv[3]);
        a[2] = CVT8(pv[4], pv[5]); a[3] = CVT8(pv[6], pv[7]);
        int myCol[4] = {pcol.x, pcol.y, pcol.z, pcol.w};
        // run-boundary flags (stripe = this wave's 16 rows; cross-stripe runs
        // stay correct via atomics). Neighbors via intra-wave shuffles.
        int cp = __shfl(myCol[3], (lane - 16) & 63, 64);
        int cn = __shfl(myCol[0], (lane + 16) & 63, 64);
        const bool h0 = (q == 0) || (myCol[0] != cp);
        const bool h1 = myCol[1] != myCol[0];
        const bool h2 = myCol[2] != myCol[1];
        const bool h3 = myCol[3] != myCol[2];
        const bool t0 = h1, t1 = h2, t2 = h3;
        const bool t3 = (q == 3) || (myCol[3] != cn);
        const bool c0m = !h0, c1m = c0m && !h1, c2m = c1m && !h2, c3m = c2m && !h3;
        const int F0 = (h0 | h1 | h2 | h3) ? 1 : 0;
        int Fp1 = __shfl(F0, (lane - 16) & 63, 64);
        const bool add1 = (q >= 1) && !F0;
        const int F1 = (F0 || ((q >= 1) && Fp1)) ? 1 : 0;
        const bool add2 = (q >= 2) && !F1;
        const bool useC = (q >= 1) && !h0;

        int tn = t + G; bool hasNext = tn < nTiles;
        if (hasNext) {   // prefetch next tile (overlaps both GEMMs)
            long ge = (long)tn * 128 + row;
            const float* px = x + (long)rowp[ge] * 64 + koff;
            const float* pe = ea + (long)eidp[ge] * 64 + koff;
            pv[0] = *(const floatx4*)(px);      pv[1] = *(const floatx4*)(px + 4);
            pv[2] = *(const floatx4*)(px + 32); pv[3] = *(const floatx4*)(px + 36);
            pv[4] = *(const floatx4*)(pe);      pv[5] = *(const floatx4*)(pe + 4);
            pv[6] = *(const floatx4*)(pe + 32); pv[7] = *(const floatx4*)(pe + 36);
            pcol = *(const int4*)&colp[(long)tn * 128 + m0];
        }
        // GEMM1
        floatx4 acc1[8];
#pragma unroll
        for (int nt = 0; nt < 8; nt++) {
            floatx4 acc = {0.f, 0.f, 0.f, 0.f};
            const int c = nt * 16 + lm;
#pragma unroll
            for (int kb = 0; kb < 4; kb++) {
                half8 b = *(const half8*)&sW1[c][kb * 32 + koff];
                acc = MFMA16(a[kb], b, acc);
            }
            acc1[nt] = acc;
        }
        // BN+ReLU, write h_bn transposed into wave-private columns of sT
#pragma unroll
        for (int nt = 0; nt < 8; nt++) {
            const int c = nt * 16 + lm;
            float sc = sScale[c], sh = sShift[c];
            half4h h;
#pragma unroll
            for (int r = 0; r < 4; r++)
                h[r] = (_Float16)fmaxf(acc1[nt][r] * sc + sh, 0.f);
            *(half4h*)&sT[c][m0] = h;
        }
        // wave-own rows/cols only -> in-wave DS ordering, no barrier
        half8 a2[4];
#pragma unroll
        for (int kb = 0; kb < 4; kb++) {
#pragma unroll
            for (int j = 0; j < 8; j++)
                a2[kb][j] = sT[kb * 32 + koff + j][row];
        }
        // GEMM2
#pragma unroll
        for (int nt = 0; nt < 8; nt++) {
            floatx4 acc = {0.f, 0.f, 0.f, 0.f};
            const int c = nt * 16 + lm;
#pragma unroll
            for (int kb = 0; kb < 4; kb++) {
                half8 b = *(const half8*)&sW2[c][kb * 32 + koff];
                acc = MFMA16(a2[kb], b, acc);
            }
            acc1[nt] = acc;   // reuse regs
        }
        // segmented-scan scatter: collapse equal-col runs, atomics at tails
#pragma unroll
        for (int nt = 0; nt < 8; nt++) {
            const int c = nt * 16 + lm;
            const int c0 = c & ~1;
            float bb = sB2[c];
            float v0 = acc1[nt][0] + bb, v1 = acc1[nt][1] + bb;
            float v2 = acc1[nt][2] + bb, v3 = acc1[nt][3] + bb;
            // in-lane segmented inclusive sums over rows m0..m0+3
            float s0 = v0;
            float s1 = h1 ? v1 : (s0 + v1);
            float s2 = h2 ? v2 : (s1 + v2);
            float s3 = h3 ? v3 : (s2 + v3);
            // cross-q segmented scan of trailing-run sums (Hillis-Steele)
            float S = s3;
            float Sp = __shfl(S, (lane - 16) & 63, 64);
            if (add1) S += Sp;
            float Sq = __shfl(S, (lane - 32) & 63, 64);
            if (add2) S += Sq;
            float Cc = __shfl(S, (lane - 16) & 63, 64);
            float C = useC ? Cc : 0.f;
            float f0 = c0m ? (s0 + C) : s0;
            float f1 = c1m ? (s1 + C) : s1;
            float f2 = c2m ? (s2 + C) : s2;
            float f3 = c3m ? (s3 + C) : s3;
            // half2 pairing across adjacent cols (lanes lm, lm^1)
            float g0 = __shfl_xor(f0, 1, 64), g1 = __shfl_xor(f1, 1, 64);
            float g2 = __shfl_xor(f2, 1, 64), g3 = __shfl_xor(f3, 1, 64);
            if ((lane & 1) == 0) {
                if (t0) unsafeAtomicAdd((__half2*)&agg[(size_t)myCol[0] * 128 + c0], __floats2half2_rn(f0, g0));
                if (t1) unsafeAtomicAdd((__half2*)&agg[(size_t)myCol[1] * 128 + c0], __floats2half2_rn(f1, g1));
            } else {
                if (t2) unsafeAtomicAdd((__half2*)&agg[(size_t)myCol[2] * 128 + c0], __floats2half2_rn(g2, f2));
                if (t3) unsafeAtomicAdd((__half2*)&agg[(size_t)myCol[3] * 128 + c0], __floats2half2_rn(g3, f3));
            }
        }
    }
}

// -------------------------------------------------------------- k_node_a ----
// h3 = concat(x, agg_f16) @ W1b (K=192); store h3 fp32 + BN stats.
__global__ __launch_bounds__(512, 2) void k_node_a(
    const float* __restrict__ x, const __half* __restrict__ agg,
    const _Float16* __restrict__ w1bt, float* __restrict__ h3,
    float* __restrict__ gsum, float* __restrict__ gsq, int N) {
    __shared__ _Float16 sIn[128][200];   // 192 + 8 pad
    __shared__ _Float16 sW[128][200];
    __shared__ float sSum[128], sSq[128];
    const int tid = threadIdx.x, lane = tid & 63, wv = tid >> 6;
    const long e0 = (long)blockIdx.x * 128;

    {   // stage W1b^T: each row 192 halves by 4 threads x 48 halves
        int n = tid >> 2, seg = (tid & 3) * 48;
        const half8* src = (const half8*)(w1bt + n * 192 + seg);
        half8* dst = (half8*)&sW[n][seg];
        dst[0] = src[0]; dst[1] = src[1]; dst[2] = src[2];
        dst[3] = src[3]; dst[4] = src[4]; dst[5] = src[5];
    }
    if (tid < 128) { sSum[tid] = 0.f; sSq[tid] = 0.f; }
    {
        int m = tid >> 2, seg = tid & 3;
        long gm = e0 + m;
        bool valid = gm < N;
        const float* srcx = x + gm * 64 + seg * 16;
        _Float16* dstx = &sIn[m][seg * 16];
#pragma unroll
        for (int i = 0; i < 4; i++) {
            floatx4 v = {0.f, 0.f, 0.f, 0.f};
            if (valid) v = ((const floatx4*)srcx)[i];
            half4h h = {(_Float16)v[0], (_Float16)v[1], (_Float16)v[2], (_Float16)v[3]};
            *(half4h*)(dstx + i * 4) = h;
        }
        const _Float16* srca = (const _Float16*)agg + gm * 128 + seg * 32;
        _Float16* dsta = &sIn[m][64 + seg * 32];
#pragma unroll
        for (int i = 0; i < 4; i++) {
            half8 v = {0, 0, 0, 0, 0, 0, 0, 0};
            if (valid) v = ((const half8*)srca)[i];
            *(half8*)(dsta + i * 8) = v;
        }
    }
    __syncthreads();

    const int lm = lane & 15, q = lane >> 4, koff = q * 8;
    half8 a[6];
#pragma unroll
    for (int kb = 0; kb < 6; kb++)
        a[kb] = *(const half8*)&sIn[wv * 16 + lm][kb * 32 + koff];
#pragma unroll
    for (int nt = 0; nt < 8; nt++) {
        floatx4 acc = {0.f, 0.f, 0.f, 0.f};
        const int c = nt * 16 + lm;
#pragma unroll
        for (int kb = 0; kb < 6; kb++) {
            half8 b = *(const half8*)&sW[c][kb * 32 + koff];
            acc = MFMA16(a[kb], b, acc);
        }
        float s  = acc[0] + acc[1] + acc[2] + acc[3];
        float ss = acc[0]*acc[0] + acc[1]*acc[1] + acc[2]*acc[2] + acc[3]*acc[3];
        s = col_reduce16(s); ss = col_reduce16(ss);
        if (q == 0) { atomicAdd(&sSum[c], s); atomicAdd(&sSq[c], ss); }
#pragma unroll
        for (int r = 0; r < 4; r++) {
            int m2 = wv * 16 + q * 4 + r;
            long gm2 = e0 + m2;
            if (gm2 < N) h3[gm2 * 128 + c] = acc[r];
        }
    }
    __syncthreads();
    if (tid < 128) {
        int slot = blockIdx.x & 15;
        unsafeAtomicAdd(&gsum[slot * 128 + tid], sSum[tid]);
        unsafeAtomicAdd(&gsq[slot * 128 + tid], sSq[tid]);
    }
}

// -------------------------------------------------------------- k_node_b ----
__global__ __launch_bounds__(512, 2) void k_node_b(
    const float* __restrict__ h3, const _Float16* __restrict__ w2bt,
    const float* __restrict__ scale, const float* __restrict__ shift,
    const float* __restrict__ b2b, float* __restrict__ out, int N) {
    __shared__ _Float16 sH[128][136];
    __shared__ _Float16 sW[64][136];
    const int tid = threadIdx.x, lane = tid & 63, wv = tid >> 6;
    const long e0 = (long)blockIdx.x * 128;

    {
        int n = tid >> 3, seg = (tid & 7) * 16;
        const half8* src = (const half8*)(w2bt + n * 128 + seg);
        half8* dst = (half8*)&sW[n][seg];
        dst[0] = src[0]; dst[1] = src[1];
    }
    {   // stage h3 with BN+ReLU applied
        int m = tid >> 2, seg = (tid & 3) * 32;
        long gm = e0 + m;
        bool valid = gm < N;
        const float* src = h3 + gm * 128 + seg;
        _Float16* dst = &sH[m][seg];
#pragma unroll
        for (int i = 0; i < 8; i++) {
            floatx4 v = {0.f, 0.f, 0.f, 0.f};
            if (valid) v = ((const floatx4*)src)[i];
            floatx4 sc = ((const floatx4*)(scale + seg))[i];
            floatx4 sh = ((const floatx4*)(shift + seg))[i];
            half4h h;
#pragma unroll
            for (int j = 0; j < 4; j++)
                h[j] = (_Float16)fmaxf(v[j] * sc[j] + sh[j], 0.f);
            *(half4h*)(dst + i * 4) = h;
        }
    }
    __syncthreads();

    const int lm = lane & 15, q = lane >> 4, koff = q * 8;
    half8 a[4];
#pragma unroll
    for (int kb = 0; kb < 4; kb++)
        a[kb] = *(const half8*)&sH[wv * 16 + lm][kb * 32 + koff];
#pragma unroll
    for (int nt = 0; nt < 4; nt++) {
        floatx4 acc = {0.f, 0.f, 0.f, 0.f};
        const int c = nt * 16 + lm;
#pragma unroll
        for (int kb = 0; kb < 4; kb++) {
            half8 b = *(const half8*)&sW[c][kb * 32 + koff];
            acc = MFMA16(a[kb], b, acc);
        }
        float bb = b2b[c];
#pragma unroll
        for (int r = 0; r < 4; r++) {
            int m2 = wv * 16 + q * 4 + r;
            long gm2 = e0 + m2;
            if (gm2 < N) out[gm2 * 64 + c] = acc[r] + bb;
        }
    }
}

// --------------------------------------------------------------- launch -----
extern "C" void kernel_launch(void* const* d_in, const int* in_sizes, int n_in,
                              void* d_out, int out_size, void* d_ws, size_t ws_size,
                              hipStream_t stream) {
    const float* x    = (const float*)d_in[0];
    const int*   eidx = (const int*)d_in[1];
    const float* ea   = (const float*)d_in[2];
    const float* W1a  = (const float*)d_in[5];
    const float* g1a  = (const float*)d_in[7];
    const float* be1a = (const float*)d_in[8];
    const float* W2a  = (const float*)d_in[9];
    const float* b2a  = (const float*)d_in[10];
    const float* W1b  = (const float*)d_in[11];
    const float* g1b  = (const float*)d_in[13];
    const float* be1b = (const float*)d_in[14];
    const float* W2b  = (const float*)d_in[15];
    const float* b2b  = (const float*)d_in[16];
    const int N = in_sizes[0] / 64;
    const int E = in_sizes[2] / 64;
    const int* rowi = eidx;
    const int* coli = eidx + E;

    // workspace layout (~49 MB)
    float* ws   = (float*)d_ws;
    __half* agg = (__half*)ws;                    // N*128 halves (= N*64 floats)
    float* h3   = ws + (size_t)N * 64;            // N*128 floats
    float* st   = h3 + (size_t)N * 128;           // stats block
    float* sumE = st,        * sqE = st + 2048;   // 16 slots x 128
    float* sumN = st + 4096, * sqN = st + 6144;
    float* scE  = st + 8192, * shE = st + 8320;
    float* scN  = st + 8448, * shN = st + 8576;
    _Float16* wh   = (_Float16*)(st + 8704);      // 16B-aligned
    _Float16* w1at = wh;
    _Float16* w2at = wh + 16384;
    _Float16* w1bt = wh + 32768;
    _Float16* w2bt = wh + 57344;
    int* cnt  = (int*)(wh + 65536);               // N
    int* cur  = cnt + N;                          // N
    int* rowp = cur + N;                          // E (src row, sorted by dest)
    int* eidp = rowp + E;                         // E (orig edge id, sorted)
    int* colp = eidp + E;                         // E (dest col, sorted)

    hipMemsetAsync(agg, 0, (size_t)N * 128 * sizeof(__half), stream);
    hipMemsetAsync(st, 0, 8192 * sizeof(float), stream);
    hipMemsetAsync(cnt, 0, (size_t)N * sizeof(int), stream);
    k_prep<<<256, 256, 0, stream>>>(W1a, W2a, W1b, W2b, w1at, w2at, w1bt, w2bt);

    // counting sort of edges by destination col
    int nbE = (E + 511) / 512;
    k_hist<<<nbE, 512, 0, stream>>>(coli, cnt, E);
    k_scan<<<1, 1024, 0, stream>>>(cnt, cur, N);
    k_scatter<<<nbE, 512, 0, stream>>>(rowi, coli, cur, rowp, eidp, colp, E);

    int nTilesE = E / 128;                        // E = 800000 -> 6250 exact
    int nbl = (N + 127) / 128;
    k_edge_stats<<<512, 512, 0, stream>>>(x, rowi, ea, w1at, sumE, sqE, nTilesE);
    k_finalize<<<1, 128, 0, stream>>>(sumE, sqE, g1a, be1a, scE, shE, (float)E);
    k_edge_mlp<<<256, 512, 0, stream>>>(x, rowp, eidp, colp, ea, w1at, w2at, scE, shE, b2a, agg, nTilesE);
    k_node_a<<<nbl, 512, 0, stream>>>(x, agg, w1bt, h3, sumN, sqN, N);
    k_finalize<<<1, 128, 0, stream>>>(sumN, sqN, g1b, be1b, scN, shN, (float)N);
    k_node_b<<<nbl, 512, 0, stream>>>(h3, w2bt, scN, shN, b2b, (float*)d_out, N);
}

// Round 4
// 732.986 us; speedup vs baseline: 1.6028x; 1.6028x over previous
//
#include <hip/hip_runtime.h>
#include <hip/hip_fp16.h>

// NodeModel: edge MLP (Lin->BN->ReLU->Lin) -> scatter_add -> node MLP (same).
// f16 MFMA 16x16x32, fp32 accumulate. Two-pass BN (stats then apply+GEMM2).
// R5: counting-sort edges by dest col; segmented-scan collapses equal-col runs
//     so only run tails issue pk-f16 atomics (WRITE 200->24 MB, mlp 353->183us).
// R6 (REVERTED): per-lane direct-global A-frags destroyed gather coalescing
//     (FETCH 190MB->1.07GB). LDS staging at 128B/thread is load-bearing.
// R7: back to R5 edge kernels. Sort path cheapened: hist fused into edge_stats
//     (hidden in its idle pipes), scatter writes ONE packed int2 {eid,
//     col<<16|row} (row,col < 65536 for this problem), finalize(edge) folded
//     into scatter. Two dispatches and ~2/3 of scatter write traffic removed.

typedef _Float16 half8  __attribute__((ext_vector_type(8)));
typedef _Float16 half4h __attribute__((ext_vector_type(4)));
typedef float    floatx4 __attribute__((ext_vector_type(4)));

#define MFMA16(a, b, c) __builtin_amdgcn_mfma_f32_16x16x32_f16(a, b, c, 0, 0, 0)

// Barrier that orders LDS only: does NOT drain vmcnt, so outstanding global
// atomics / prefetch loads ride across it.
#define LDS_BARRIER() do { \
    asm volatile("s_waitcnt lgkmcnt(0)" ::: "memory"); \
    __builtin_amdgcn_s_barrier(); \
} while (0)

__device__ __forceinline__ float col_reduce16(float v) {
    v += __shfl_xor(v, 16, 64);
    v += __shfl_xor(v, 32, 64);
    return v;
}

// ---------------------------------------------------------------- k_prep ----
__global__ void k_prep(const float* __restrict__ w1a, const float* __restrict__ w2a,
                       const float* __restrict__ w1b, const float* __restrict__ w2b,
                       _Float16* __restrict__ w1at, _Float16* __restrict__ w2at,
                       _Float16* __restrict__ w1bt, _Float16* __restrict__ w2bt) {
    int i = blockIdx.x * 256 + threadIdx.x;           // 65536 total
    if (i < 16384) {
        int n = i >> 7, k = i & 127;
        w1at[n * 128 + k] = (_Float16)w1a[k * 128 + n];
    } else if (i < 32768) {
        int j = i - 16384; int n = j >> 7, k = j & 127;
        w2at[n * 128 + k] = (_Float16)w2a[k * 128 + n];
    } else if (i < 57344) {
        int j = i - 32768; int n = j / 192, k = j - n * 192;
        w1bt[n * 192 + k] = (_Float16)w1b[k * 128 + n];
    } else if (i < 65536) {
        int j = i - 57344; int n = j >> 7, k = j & 127;
        w2bt[n * 128 + k] = (_Float16)w2b[k * 64 + n];
    }
}

// ---------------------------------------------------------------- k_scan ----
__global__ __launch_bounds__(1024) void k_scan(const int* __restrict__ cnt,
                                               int* __restrict__ cur, int N) {
    __shared__ int sp[1024];
    int t = threadIdx.x;
    int chunk = (N + 1023) >> 10;
    int base = t * chunk;
    int s = 0;
    for (int j = 0; j < chunk; j++) {
        int idx = base + j;
        if (idx < N) s += cnt[idx];
    }
    sp[t] = s; __syncthreads();
    for (int off = 1; off < 1024; off <<= 1) {
        int v = (t >= off) ? sp[t - off] : 0;
        __syncthreads();
        sp[t] += v;
        __syncthreads();
    }
    int run = sp[t] - s;          // exclusive prefix at chunk start
    for (int j = 0; j < chunk; j++) {
        int idx = base + j;
        if (idx < N) { cur[idx] = run; run += cnt[idx]; }
    }
}

// --------------------------------------------------------- k_scatter_fin ----
// Scatter edges into dest-sorted order as packed int2 {eid, col<<16|row}
// (single 8B store per edge). Block 0 also finalizes the edge-BN scale/shift
// (independent of the scatter data; stats kernel already completed).
__global__ void k_scatter_fin(const int* __restrict__ rowi, const int* __restrict__ coli,
                              int* __restrict__ cur, int2* __restrict__ pairs,
                              const float* __restrict__ sums, const float* __restrict__ sqs,
                              const float* __restrict__ gamma, const float* __restrict__ beta,
                              float* __restrict__ scale, float* __restrict__ shift,
                              float count, int E) {
    int i = blockIdx.x * 512 + threadIdx.x;
    if (i < E) {
        int c = coli[i];
        int p = atomicAdd(&cur[c], 1);
        pairs[p] = make_int2(i, (c << 16) | rowi[i]);
    }
    if (blockIdx.x == 0 && threadIdx.x < 128) {
        int j = threadIdx.x;
        float s = 0.f, ssq = 0.f;
        for (int k = 0; k < 16; k++) { s += sums[k * 128 + j]; ssq += sqs[k * 128 + j]; }
        float mu = s / count;
        float var = ssq / count - mu * mu;
        float sc = gamma[j] * rsqrtf(var + 1e-5f);
        scale[j] = sc;
        shift[j] = beta[j] - mu * sc;
    }
}

// ---------------------------------------------------------- k_edge_stats ----
// Pass 1: h1 = concat(x[row],ea) @ W1a; per-lane reg accumulation of col
// sum/sumsq; one global atomic per col per block at the end. Also builds the
// destination histogram (hist fused: hidden in this kernel's idle pipes).
// LDS ~70 KB -> 2 blocks/CU. Reg-prefetch of next tile overlaps GEMM1.
__global__ __launch_bounds__(512, 4) void k_edge_stats(
    const float* __restrict__ x, const int* __restrict__ rowi,
    const int* __restrict__ coli,
    const float* __restrict__ ea, const _Float16* __restrict__ w1t,
    float* __restrict__ gsum, float* __restrict__ gsq,
    int* __restrict__ cnt, int nTiles) {
    __shared__ _Float16 sW[128][136];
    __shared__ _Float16 sIn[128][136];
    const int tid = threadIdx.x, lane = tid & 63, wv = tid >> 6;
    const int lm = lane & 15, q = lane >> 4, koff = q * 8;
    const int G = gridDim.x;
    const int e = tid >> 2, part = tid & 3;

    {   // stage W1^T once
        int n = tid >> 2, seg = (tid & 3) * 32;
        const half8* src = (const half8*)(w1t + n * 128 + seg);
        half8* dst = (half8*)&sW[n][seg];
        dst[0] = src[0]; dst[1] = src[1]; dst[2] = src[2]; dst[3] = src[3];
    }
    float sAcc[8], ssAcc[8];
#pragma unroll
    for (int i = 0; i < 8; i++) { sAcc[i] = 0.f; ssAcc[i] = 0.f; }

    int t = blockIdx.x;
    floatx4 pv[8];
    int hc = 0;
    {   // prologue load of tile t
        long ge = (long)t * 128 + e;
        const float* src = (part < 2) ? x + (long)rowi[ge] * 64 + part * 32
                                      : ea + ge * 64 + (part - 2) * 32;
#pragma unroll
        for (int i = 0; i < 8; i++) pv[i] = ((const floatx4*)src)[i];
        if (part == 0) hc = coli[ge];
    }
    for (; t < nTiles; t += G) {
        {   // regs -> LDS (convert f32->f16)
            _Float16* dst = &sIn[e][part * 32];
#pragma unroll
            for (int i = 0; i < 8; i++) {
                half4h h = {(_Float16)pv[i][0], (_Float16)pv[i][1],
                            (_Float16)pv[i][2], (_Float16)pv[i][3]};
                *(half4h*)(dst + i * 4) = h;
            }
        }
        LDS_BARRIER();
        if (part == 0) atomicAdd(&cnt[hc], 1);     // fused hist (fire-and-forget)
        int tn = t + G;
        if (tn < nTiles) {   // prefetch next tile into regs (overlaps GEMM1)
            long ge = (long)tn * 128 + e;
            const float* src = (part < 2) ? x + (long)rowi[ge] * 64 + part * 32
                                          : ea + ge * 64 + (part - 2) * 32;
#pragma unroll
            for (int i = 0; i < 8; i++) pv[i] = ((const floatx4*)src)[i];
            if (part == 0) hc = coli[ge];
        }
        half8 a[4];
#pragma unroll
        for (int kb = 0; kb < 4; kb++)
            a[kb] = *(const half8*)&sIn[wv * 16 + lm][kb * 32 + koff];
#pragma unroll
        for (int nt = 0; nt < 8; nt++) {
            floatx4 acc = {0.f, 0.f, 0.f, 0.f};
            const int c = nt * 16 + lm;
#pragma unroll
            for (int kb = 0; kb < 4; kb++) {
                half8 b = *(const half8*)&sW[c][kb * 32 + koff];
                acc = MFMA16(a[kb], b, acc);
            }
            sAcc[nt]  += acc[0] + acc[1] + acc[2] + acc[3];
            ssAcc[nt] += acc[0]*acc[0] + acc[1]*acc[1] + acc[2]*acc[2] + acc[3]*acc[3];
        }
        LDS_BARRIER();
    }
#pragma unroll
    for (int nt = 0; nt < 8; nt++) {
        float s  = col_reduce16(sAcc[nt]);
        float ss = col_reduce16(ssAcc[nt]);
        if (q == 0) {
            int c = nt * 16 + lm;
            int slot = (blockIdx.x * 8 + wv) & 15;
            unsafeAtomicAdd(&gsum[slot * 128 + c], s);
            unsafeAtomicAdd(&gsq[slot * 128 + c], ss);
        }
    }
}

// ------------------------------------------------------------ k_finalize ----
__global__ void k_finalize(const float* __restrict__ sums, const float* __restrict__ sqs,
                           const float* __restrict__ gamma, const float* __restrict__ beta,
                           float* __restrict__ scale, float* __restrict__ shift, float count) {
    int i = threadIdx.x;   // 128
    float s = 0.f, ssq = 0.f;
    for (int j = 0; j < 16; j++) { s += sums[j * 128 + i]; ssq += sqs[j * 128 + i]; }
    float mu = s / count;
    float var = ssq / count - mu * mu;      // biased, matches torch/jax ref
    float sc = gamma[i] * rsqrtf(var + 1e-5f);
    scale[i] = sc;
    shift[i] = beta[i] - mu * sc;
}

// ------------------------------------------------------------ k_edge_mlp ----
// Pass 2 on SORTED edges (packed pairs): recompute h1, BN+ReLU (in-LDS
// transpose), GEMM2(+b2a), then collapse equal-col runs per 16-row wave
// stripe with a segmented scan; only run tails issue pk-f16 atomics.
__global__ __launch_bounds__(512, 2) void k_edge_mlp(
    const float* __restrict__ x, const int2* __restrict__ pairs,
    const float* __restrict__ ea, const _Float16* __restrict__ w1t, const _Float16* __restrict__ w2t,
    const float* __restrict__ scale, const float* __restrict__ shift, const float* __restrict__ b2a,
    __half* __restrict__ agg, int nTiles) {
    __shared__ _Float16 sW1[128][136];
    __shared__ _Float16 sW2[128][136];
    __shared__ _Float16 sIn[2][128][136];   // input tile / h_bn transpose scratch
    __shared__ float sScale[128], sShift[128], sB2[128];
    __shared__ int sCol[2][128];
    const int tid = threadIdx.x, lane = tid & 63, wv = tid >> 6;
    const int lm = lane & 15, q = lane >> 4, koff = q * 8;
    const int G = gridDim.x;
    const int e = tid >> 2, part = tid & 3;

    {   // stage both weight matrices once
        int n = tid >> 2, seg = (tid & 3) * 32;
        const half8* s1 = (const half8*)(w1t + n * 128 + seg);
        half8* d1 = (half8*)&sW1[n][seg];
        d1[0] = s1[0]; d1[1] = s1[1]; d1[2] = s1[2]; d1[3] = s1[3];
        const half8* s2 = (const half8*)(w2t + n * 128 + seg);
        half8* d2 = (half8*)&sW2[n][seg];
        d2[0] = s2[0]; d2[1] = s2[1]; d2[2] = s2[2]; d2[3] = s2[3];
    }
    if (tid < 128) { sScale[tid] = scale[tid]; sShift[tid] = shift[tid]; sB2[tid] = b2a[tid]; }

    int t = blockIdx.x;
    {   // prologue: stage tile t into buf 0
        long ge = (long)t * 128 + e;
        int2 pr = pairs[ge];
        const float* src = (part < 2) ? x + (long)(pr.y & 0xFFFF) * 64 + part * 32
                                      : ea + (long)pr.x * 64 + (part - 2) * 32;
        _Float16* dst = &sIn[0][e][part * 32];
#pragma unroll
        for (int i = 0; i < 8; i++) {
            floatx4 v = ((const floatx4*)src)[i];
            half4h h = {(_Float16)v[0], (_Float16)v[1], (_Float16)v[2], (_Float16)v[3]};
            *(half4h*)(dst + i * 4) = h;
        }
        if (tid < 128) sCol[0][tid] = (int)(((unsigned)pairs[(long)t * 128 + tid].y) >> 16);
    }
    __syncthreads();
    int p = 0;
    for (; t < nTiles; t += G) {
        half8 a[4];
#pragma unroll
        for (int kb = 0; kb < 4; kb++)
            a[kb] = *(const half8*)&sIn[p][wv * 16 + lm][kb * 32 + koff];
        int myCol[4];
        const int m0 = wv * 16 + q * 4;
#pragma unroll
        for (int r = 0; r < 4; r++) myCol[r] = sCol[p][m0 + r];
        // run-boundary flags for this stripe (rows sorted by dest col).
        // Pieces are per-stripe; cross-stripe runs stay correct via atomics.
        int cp = sCol[p][(q > 0) ? m0 - 1 : m0];
        int cn = sCol[p][(q < 3) ? m0 + 4 : m0 + 3];
        const bool h0 = (q == 0) || (myCol[0] != cp);
        const bool h1 = myCol[1] != myCol[0];
        const bool h2 = myCol[2] != myCol[1];
        const bool h3 = myCol[3] != myCol[2];
        const bool t0 = h1, t1 = h2, t2 = h3;
        const bool t3 = (q == 3) || (myCol[3] != cn);
        const bool c0m = !h0, c1m = c0m && !h1, c2m = c1m && !h2, c3m = c2m && !h3;
        const int F0 = (h0 | h1 | h2 | h3) ? 1 : 0;
        int Fp1 = __shfl(F0, (lane - 16) & 63, 64);
        const bool add1 = (q >= 1) && !F0;
        const int F1 = (F0 || ((q >= 1) && Fp1)) ? 1 : 0;
        const bool add2 = (q >= 2) && !F1;
        const bool useC = (q >= 1) && !h0;

        int tn = t + G; bool hasNext = tn < nTiles;
        floatx4 pv[8]; int pcol = 0;
        if (hasNext) {   // prefetch next tile into regs (overlaps both GEMMs)
            long ge = (long)tn * 128 + e;
            int2 pr = pairs[ge];
            const float* src = (part < 2) ? x + (long)(pr.y & 0xFFFF) * 64 + part * 32
                                          : ea + (long)pr.x * 64 + (part - 2) * 32;
#pragma unroll
            for (int i = 0; i < 8; i++) pv[i] = ((const floatx4*)src)[i];
            if (tid < 128) pcol = (int)(((unsigned)pairs[(long)tn * 128 + tid].y) >> 16);
        }
        // GEMM1
        floatx4 acc1[8];
#pragma unroll
        for (int nt = 0; nt < 8; nt++) {
            floatx4 acc = {0.f, 0.f, 0.f, 0.f};
            const int c = nt * 16 + lm;
#pragma unroll
            for (int kb = 0; kb < 4; kb++) {
                half8 b = *(const half8*)&sW1[c][kb * 32 + koff];
                acc = MFMA16(a[kb], b, acc);
            }
            acc1[nt] = acc;
        }
        LDS_BARRIER();   // all waves done reading sIn[p]; prefetch stays in flight

        // BN+ReLU, write h_bn transposed into sIn[p]
        _Float16(*sT)[136] = sIn[p];
#pragma unroll
        for (int nt = 0; nt < 8; nt++) {
            const int c = nt * 16 + lm;
            float sc = sScale[c], sh = sShift[c];
            half4h h;
#pragma unroll
            for (int r = 0; r < 4; r++)
                h[r] = (_Float16)fmaxf(acc1[nt][r] * sc + sh, 0.f);
            *(half4h*)&sT[c][wv * 16 + q * 4] = h;
        }
        // own-wave rows only -> no barrier (in-wave DS ordering)
        half8 a2[4];
#pragma unroll
        for (int kb = 0; kb < 4; kb++) {
#pragma unroll
            for (int j = 0; j < 8; j++)
                a2[kb][j] = sT[kb * 32 + koff + j][wv * 16 + lm];
        }
        // GEMM2
#pragma unroll
        for (int nt = 0; nt < 8; nt++) {
            floatx4 acc = {0.f, 0.f, 0.f, 0.f};
            const int c = nt * 16 + lm;
#pragma unroll
            for (int kb = 0; kb < 4; kb++) {
                half8 b = *(const half8*)&sW2[c][kb * 32 + koff];
                acc = MFMA16(a2[kb], b, acc);
            }
            acc1[nt] = acc;   // reuse regs
        }
        // store prefetched tile into the other buffer
        if (hasNext) {
            _Float16* dst = &sIn[p ^ 1][e][part * 32];
#pragma unroll
            for (int i = 0; i < 8; i++) {
                half4h h = {(_Float16)pv[i][0], (_Float16)pv[i][1],
                            (_Float16)pv[i][2], (_Float16)pv[i][3]};
                *(half4h*)(dst + i * 4) = h;
            }
            if (tid < 128) sCol[p ^ 1][tid] = pcol;
        }
        // segmented-scan scatter: collapse equal-col runs, atomics at tails
#pragma unroll
        for (int nt = 0; nt < 8; nt++) {
            const int c = nt * 16 + lm;
            const int c0 = c & ~1;
            float bb = sB2[c];
            float v0 = acc1[nt][0] + bb, v1 = acc1[nt][1] + bb;
            float v2 = acc1[nt][2] + bb, v3 = acc1[nt][3] + bb;
            // in-lane segmented inclusive sums over rows m0..m0+3
            float s0 = v0;
            float s1 = h1 ? v1 : (s0 + v1);
            float s2 = h2 ? v2 : (s1 + v2);
            float s3 = h3 ? v3 : (s2 + v3);
            // cross-q segmented scan of trailing-run sums (Hillis-Steele)
            float S = s3;
            float Sp = __shfl(S, (lane - 16) & 63, 64);
            if (add1) S += Sp;
            float Sq = __shfl(S, (lane - 32) & 63, 64);
            if (add2) S += Sq;
            float Cc = __shfl(S, (lane - 16) & 63, 64);
            float C = useC ? Cc : 0.f;
            float f0 = c0m ? (s0 + C) : s0;
            float f1 = c1m ? (s1 + C) : s1;
            float f2 = c2m ? (s2 + C) : s2;
            float f3 = c3m ? (s3 + C) : s3;
            // half2 pairing across adjacent cols (lanes lm, lm^1)
            float g0 = __shfl_xor(f0, 1, 64), g1 = __shfl_xor(f1, 1, 64);
            float g2 = __shfl_xor(f2, 1, 64), g3 = __shfl_xor(f3, 1, 64);
            if ((lane & 1) == 0) {
                if (t0) unsafeAtomicAdd((__half2*)&agg[(size_t)myCol[0] * 128 + c0], __floats2half2_rn(f0, g0));
                if (t1) unsafeAtomicAdd((__half2*)&agg[(size_t)myCol[1] * 128 + c0], __floats2half2_rn(f1, g1));
            } else {
                if (t2) unsafeAtomicAdd((__half2*)&agg[(size_t)myCol[2] * 128 + c0], __floats2half2_rn(g2, f2));
                if (t3) unsafeAtomicAdd((__half2*)&agg[(size_t)myCol[3] * 128 + c0], __floats2half2_rn(g3, f3));
            }
        }
        LDS_BARRIER();   // buf p^1 staged + visible; atomics ride across
        p ^= 1;
    }
}

// -------------------------------------------------------------- k_node_a ----
// h3 = concat(x, agg_f16) @ W1b (K=192); store h3 fp32 + BN stats.
__global__ __launch_bounds__(512, 2) void k_node_a(
    const float* __restrict__ x, const __half* __restrict__ agg,
    const _Float16* __restrict__ w1bt, float* __restrict__ h3,
    float* __restrict__ gsum, float* __restrict__ gsq, int N) {
    __shared__ _Float16 sIn[128][200];   // 192 + 8 pad
    __shared__ _Float16 sW[128][200];
    __shared__ float sSum[128], sSq[128];
    const int tid = threadIdx.x, lane = tid & 63, wv = tid >> 6;
    const long e0 = (long)blockIdx.x * 128;

    {   // stage W1b^T: each row 192 halves by 4 threads x 48 halves
        int n = tid >> 2, seg = (tid & 3) * 48;
        const half8* src = (const half8*)(w1bt + n * 192 + seg);
        half8* dst = (half8*)&sW[n][seg];
        dst[0] = src[0]; dst[1] = src[1]; dst[2] = src[2];
        dst[3] = src[3]; dst[4] = src[4]; dst[5] = src[5];
    }
    if (tid < 128) { sSum[tid] = 0.f; sSq[tid] = 0.f; }
    {
        int m = tid >> 2, seg = tid & 3;
        long gm = e0 + m;
        bool valid = gm < N;
        const float* srcx = x + gm * 64 + seg * 16;
        _Float16* dstx = &sIn[m][seg * 16];
#pragma unroll
        for (int i = 0; i < 4; i++) {
            floatx4 v = {0.f, 0.f, 0.f, 0.f};
            if (valid) v = ((const floatx4*)srcx)[i];
            half4h h = {(_Float16)v[0], (_Float16)v[1], (_Float16)v[2], (_Float16)v[3]};
            *(half4h*)(dstx + i * 4) = h;
        }
        const _Float16* srca = (const _Float16*)agg + gm * 128 + seg * 32;
        _Float16* dsta = &sIn[m][64 + seg * 32];
#pragma unroll
        for (int i = 0; i < 4; i++) {
            half8 v = {0, 0, 0, 0, 0, 0, 0, 0};
            if (valid) v = ((const half8*)srca)[i];
            *(half8*)(dsta + i * 8) = v;
        }
    }
    __syncthreads();

    const int lm = lane & 15, q = lane >> 4, koff = q * 8;
    half8 a[6];
#pragma unroll
    for (int kb = 0; kb < 6; kb++)
        a[kb] = *(const half8*)&sIn[wv * 16 + lm][kb * 32 + koff];
#pragma unroll
    for (int nt = 0; nt < 8; nt++) {
        floatx4 acc = {0.f, 0.f, 0.f, 0.f};
        const int c = nt * 16 + lm;
#pragma unroll
        for (int kb = 0; kb < 6; kb++) {
            half8 b = *(const half8*)&sW[c][kb * 32 + koff];
            acc = MFMA16(a[kb], b, acc);
        }
        float s  = acc[0] + acc[1] + acc[2] + acc[3];
        float ss = acc[0]*acc[0] + acc[1]*acc[1] + acc[2]*acc[2] + acc[3]*acc[3];
        s = col_reduce16(s); ss = col_reduce16(ss);
        if (q == 0) { atomicAdd(&sSum[c], s); atomicAdd(&sSq[c], ss); }
#pragma unroll
        for (int r = 0; r < 4; r++) {
            int m2 = wv * 16 + q * 4 + r;
            long gm2 = e0 + m2;
            if (gm2 < N) h3[gm2 * 128 + c] = acc[r];
        }
    }
    __syncthreads();
    if (tid < 128) {
        int slot = blockIdx.x & 15;
        unsafeAtomicAdd(&gsum[slot * 128 + tid], sSum[tid]);
        unsafeAtomicAdd(&gsq[slot * 128 + tid], sSq[tid]);
    }
}

// -------------------------------------------------------------- k_node_b ----
__global__ __launch_bounds__(512, 2) void k_node_b(
    const float* __restrict__ h3, const _Float16* __restrict__ w2bt,
    const float* __restrict__ scale, const float* __restrict__ shift,
    const float* __restrict__ b2b, float* __restrict__ out, int N) {
    __shared__ _Float16 sH[128][136];
    __shared__ _Float16 sW[64][136];
    const int tid = threadIdx.x, lane = tid & 63, wv = tid >> 6;
    const long e0 = (long)blockIdx.x * 128;

    {
        int n = tid >> 3, seg = (tid & 7) * 16;
        const half8* src = (const half8*)(w2bt + n * 128 + seg);
        half8* dst = (half8*)&sW[n][seg];
        dst[0] = src[0]; dst[1] = src[1];
    }
    {   // stage h3 with BN+ReLU applied
        int m = tid >> 2, seg = (tid & 3) * 32;
        long gm = e0 + m;
        bool valid = gm < N;
        const float* src = h3 + gm * 128 + seg;
        _Float16* dst = &sH[m][seg];
#pragma unroll
        for (int i = 0; i < 8; i++) {
            floatx4 v = {0.f, 0.f, 0.f, 0.f};
            if (valid) v = ((const floatx4*)src)[i];
            floatx4 sc = ((const floatx4*)(scale + seg))[i];
            floatx4 sh = ((const floatx4*)(shift + seg))[i];
            half4h h;
#pragma unroll
            for (int j = 0; j < 4; j++)
                h[j] = (_Float16)fmaxf(v[j] * sc[j] + sh[j], 0.f);
            *(half4h*)(dst + i * 4) = h;
        }
    }
    __syncthreads();

    const int lm = lane & 15, q = lane >> 4, koff = q * 8;
    half8 a[4];
#pragma unroll
    for (int kb = 0; kb < 4; kb++)
        a[kb] = *(const half8*)&sH[wv * 16 + lm][kb * 32 + koff];
#pragma unroll
    for (int nt = 0; nt < 4; nt++) {
        floatx4 acc = {0.f, 0.f, 0.f, 0.f};
        const int c = nt * 16 + lm;
#pragma unroll
        for (int kb = 0; kb < 4; kb++) {
            half8 b = *(const half8*)&sW[c][kb * 32 + koff];
            acc = MFMA16(a[kb], b, acc);
        }
        float bb = b2b[c];
#pragma unroll
        for (int r = 0; r < 4; r++) {
            int m2 = wv * 16 + q * 4 + r;
            long gm2 = e0 + m2;
            if (gm2 < N) out[gm2 * 64 + c] = acc[r] + bb;
        }
    }
}

// --------------------------------------------------------------- launch -----
extern "C" void kernel_launch(void* const* d_in, const int* in_sizes, int n_in,
                              void* d_out, int out_size, void* d_ws, size_t ws_size,
                              hipStream_t stream) {
    const float* x    = (const float*)d_in[0];
    const int*   eidx = (const int*)d_in[1];
    const float* ea   = (const float*)d_in[2];
    const float* W1a  = (const float*)d_in[5];
    const float* g1a  = (const float*)d_in[7];
    const float* be1a = (const float*)d_in[8];
    const float* W2a  = (const float*)d_in[9];
    const float* b2a  = (const float*)d_in[10];
    const float* W1b  = (const float*)d_in[11];
    const float* g1b  = (const float*)d_in[13];
    const float* be1b = (const float*)d_in[14];
    const float* W2b  = (const float*)d_in[15];
    const float* b2b  = (const float*)d_in[16];
    const int N = in_sizes[0] / 64;
    const int E = in_sizes[2] / 64;
    const int* rowi = eidx;
    const int* coli = eidx + E;

    // workspace layout (~46 MB)
    float* ws   = (float*)d_ws;
    __half* agg = (__half*)ws;                    // N*128 halves (= N*64 floats)
    float* h3   = ws + (size_t)N * 64;            // N*128 floats
    float* st   = h3 + (size_t)N * 128;           // stats block
    float* sumE = st,        * sqE = st + 2048;   // 16 slots x 128
    float* sumN = st + 4096, * sqN = st + 6144;
    float* scE  = st + 8192, * shE = st + 8320;
    float* scN  = st + 8448, * shN = st + 8576;
    _Float16* wh   = (_Float16*)(st + 8704);      // 16B-aligned
    _Float16* w1at = wh;
    _Float16* w2at = wh + 16384;
    _Float16* w1bt = wh + 32768;
    _Float16* w2bt = wh + 57344;
    int* cnt  = (int*)(wh + 65536);               // N
    int* cur  = cnt + N;                          // N
    int2* pairs = (int2*)(cur + N);               // E x {eid, col<<16|row}

    hipMemsetAsync(agg, 0, (size_t)N * 128 * sizeof(__half), stream);
    hipMemsetAsync(st, 0, 8192 * sizeof(float), stream);
    hipMemsetAsync(cnt, 0, (size_t)N * sizeof(int), stream);
    k_prep<<<256, 256, 0, stream>>>(W1a, W2a, W1b, W2b, w1at, w2at, w1bt, w2bt);

    int nTilesE = E / 128;                        // E = 800000 -> 6250 exact
    int nbl = (N + 127) / 128;
    int nbE = (E + 511) / 512;
    // pass 1 (stats + fused dest histogram)
    k_edge_stats<<<512, 512, 0, stream>>>(x, rowi, coli, ea, w1at, sumE, sqE, cnt, nTilesE);
    // sort finish: scan + scatter(+edge-BN finalize)
    k_scan<<<1, 1024, 0, stream>>>(cnt, cur, N);
    k_scatter_fin<<<nbE, 512, 0, stream>>>(rowi, coli, cur, pairs, sumE, sqE, g1a, be1a,
                                           scE, shE, (float)E, E);
    // pass 2 (BN+GEMM2+reduced scatter)
    k_edge_mlp<<<256, 512, 0, stream>>>(x, pairs, ea, w1at, w2at, scE, shE, b2a, agg, nTilesE);
    k_node_a<<<nbl, 512, 0, stream>>>(x, agg, w1bt, h3, sumN, sqN, N);
    k_finalize<<<1, 128, 0, stream>>>(sumN, sqN, g1b, be1b, scN, shN, (float)N);
    k_node_b<<<nbl, 512, 0, stream>>>(h3, w2bt, scN, shN, b2b, (float*)d_out, N);
}

// Round 5
// 713.918 us; speedup vs baseline: 1.6456x; 1.0267x over previous
//
#include <hip/hip_runtime.h>
#include <hip/hip_fp16.h>

// NodeModel: edge MLP (Lin->BN->ReLU->Lin) -> scatter_add -> node MLP (same).
// f16 MFMA 16x16x32, fp32 accumulate. Two-pass BN (stats then apply+GEMM2).
// R5: counting-sort edges by dest col; segmented-scan collapses equal-col runs
//     so only run tails issue pk-f16 atomics (WRITE 200->24 MB).
// R6 (REVERTED): per-lane direct-global A-frags destroyed gather coalescing.
// R7: packed int2 sort payload; hist fused into edge_stats.
// R8: BARRIER-FREE edge kernels. Staging rows are wave-aligned (thread tid
//     stages row tid>>2; wave wv stages rows 16wv..16wv+15 = exactly its own
//     A-frag rows), and the transpose scratch is wave-private too. So the
//     per-tile block barriers + double buffer were pure convoy overhead:
//     replaced with per-wave lgkmcnt-only waits. Transpose switched from
//     bank-collided u16 column reads to row-major h_bn (paired half2 writes
//     + b128 row reads that ARE the GEMM2 A-frags). BN consts hoisted to regs.

typedef _Float16 half8  __attribute__((ext_vector_type(8)));
typedef _Float16 half4h __attribute__((ext_vector_type(4)));
typedef _Float16 half2h __attribute__((ext_vector_type(2)));
typedef float    floatx4 __attribute__((ext_vector_type(4)));

#define MFMA16(a, b, c) __builtin_amdgcn_mfma_f32_16x16x32_f16(a, b, c, 0, 0, 0)

// Wave-local LDS drain: staged rows are wave-private, so no s_barrier needed.
#define LGKM0() asm volatile("s_waitcnt lgkmcnt(0)" ::: "memory")

__device__ __forceinline__ float col_reduce16(float v) {
    v += __shfl_xor(v, 16, 64);
    v += __shfl_xor(v, 32, 64);
    return v;
}

// ---------------------------------------------------------------- k_prep ----
__global__ void k_prep(const float* __restrict__ w1a, const float* __restrict__ w2a,
                       const float* __restrict__ w1b, const float* __restrict__ w2b,
                       _Float16* __restrict__ w1at, _Float16* __restrict__ w2at,
                       _Float16* __restrict__ w1bt, _Float16* __restrict__ w2bt) {
    int i = blockIdx.x * 256 + threadIdx.x;           // 65536 total
    if (i < 16384) {
        int n = i >> 7, k = i & 127;
        w1at[n * 128 + k] = (_Float16)w1a[k * 128 + n];
    } else if (i < 32768) {
        int j = i - 16384; int n = j >> 7, k = j & 127;
        w2at[n * 128 + k] = (_Float16)w2a[k * 128 + n];
    } else if (i < 57344) {
        int j = i - 32768; int n = j / 192, k = j - n * 192;
        w1bt[n * 192 + k] = (_Float16)w1b[k * 128 + n];
    } else if (i < 65536) {
        int j = i - 57344; int n = j >> 7, k = j & 127;
        w2bt[n * 128 + k] = (_Float16)w2b[k * 64 + n];
    }
}

// ---------------------------------------------------------------- k_scan ----
__global__ __launch_bounds__(1024) void k_scan(const int* __restrict__ cnt,
                                               int* __restrict__ cur, int N) {
    __shared__ int sp[1024];
    int t = threadIdx.x;
    int chunk = (N + 1023) >> 10;
    int base = t * chunk;
    int s = 0;
    for (int j = 0; j < chunk; j++) {
        int idx = base + j;
        if (idx < N) s += cnt[idx];
    }
    sp[t] = s; __syncthreads();
    for (int off = 1; off < 1024; off <<= 1) {
        int v = (t >= off) ? sp[t - off] : 0;
        __syncthreads();
        sp[t] += v;
        __syncthreads();
    }
    int run = sp[t] - s;          // exclusive prefix at chunk start
    for (int j = 0; j < chunk; j++) {
        int idx = base + j;
        if (idx < N) { cur[idx] = run; run += cnt[idx]; }
    }
}

// --------------------------------------------------------- k_scatter_fin ----
// Scatter edges into dest-sorted order as packed int2 {eid, col<<16|row}.
// Block 0 also finalizes the edge-BN scale/shift (stats kernel already done).
__global__ void k_scatter_fin(const int* __restrict__ rowi, const int* __restrict__ coli,
                              int* __restrict__ cur, int2* __restrict__ pairs,
                              const float* __restrict__ sums, const float* __restrict__ sqs,
                              const float* __restrict__ gamma, const float* __restrict__ beta,
                              float* __restrict__ scale, float* __restrict__ shift,
                              float count, int E) {
    int i = blockIdx.x * 512 + threadIdx.x;
    if (i < E) {
        int c = coli[i];
        int p = atomicAdd(&cur[c], 1);
        pairs[p] = make_int2(i, (c << 16) | rowi[i]);
    }
    if (blockIdx.x == 0 && threadIdx.x < 128) {
        int j = threadIdx.x;
        float s = 0.f, ssq = 0.f;
        for (int k = 0; k < 16; k++) { s += sums[k * 128 + j]; ssq += sqs[k * 128 + j]; }
        float mu = s / count;
        float var = ssq / count - mu * mu;
        float sc = gamma[j] * rsqrtf(var + 1e-5f);
        scale[j] = sc;
        shift[j] = beta[j] - mu * sc;
    }
}

// ---------------------------------------------------------- k_edge_stats ----
// Pass 1: h1 = concat(x[row],ea) @ W1a; per-lane reg accumulation of col
// sum/sumsq; fused dest histogram. BARRIER-FREE: staging rows are
// wave-private (thread tid -> row tid>>2, wave wv -> rows 16wv..16wv+15,
// exactly its A-frag rows), so only lgkmcnt waits; waves self-pipeline.
__global__ __launch_bounds__(512, 4) void k_edge_stats(
    const float* __restrict__ x, const int* __restrict__ rowi,
    const int* __restrict__ coli,
    const float* __restrict__ ea, const _Float16* __restrict__ w1t,
    float* __restrict__ gsum, float* __restrict__ gsq,
    int* __restrict__ cnt, int nTiles) {
    __shared__ _Float16 sW[128][136];
    __shared__ _Float16 sIn[128][136];
    const int tid = threadIdx.x, lane = tid & 63, wv = tid >> 6;
    const int lm = lane & 15, q = lane >> 4, koff = q * 8;
    const int G = gridDim.x;
    const int e = tid >> 2, part = tid & 3;
    const int row = wv * 16 + lm;

    {   // stage W1^T once
        int n = tid >> 2, seg = (tid & 3) * 32;
        const half8* src = (const half8*)(w1t + n * 128 + seg);
        half8* dst = (half8*)&sW[n][seg];
        dst[0] = src[0]; dst[1] = src[1]; dst[2] = src[2]; dst[3] = src[3];
    }
    __syncthreads();   // weights visible; the only block-wide barrier

    float sAcc[8], ssAcc[8];
#pragma unroll
    for (int i = 0; i < 8; i++) { sAcc[i] = 0.f; ssAcc[i] = 0.f; }

    int t = blockIdx.x;
    floatx4 pv[8];
    int hc = 0;
    {   // prologue load of tile t
        long ge = (long)t * 128 + e;
        const float* src = (part < 2) ? x + (long)rowi[ge] * 64 + part * 32
                                      : ea + ge * 64 + (part - 2) * 32;
#pragma unroll
        for (int i = 0; i < 8; i++) pv[i] = ((const floatx4*)src)[i];
        if (part == 0) hc = coli[ge];
    }
    for (; t < nTiles; t += G) {
        {   // regs -> LDS (convert f32->f16), wave-private rows
            _Float16* dst = &sIn[e][part * 32];
#pragma unroll
            for (int i = 0; i < 8; i++) {
                half4h h = {(_Float16)pv[i][0], (_Float16)pv[i][1],
                            (_Float16)pv[i][2], (_Float16)pv[i][3]};
                *(half4h*)(dst + i * 4) = h;
            }
        }
        if (part == 0) atomicAdd(&cnt[hc], 1);     // fused hist (fire-and-forget)
        int tn = t + G;
        if (tn < nTiles) {   // prefetch next tile into regs (overlaps GEMM1)
            long ge = (long)tn * 128 + e;
            const float* src = (part < 2) ? x + (long)rowi[ge] * 64 + part * 32
                                          : ea + ge * 64 + (part - 2) * 32;
#pragma unroll
            for (int i = 0; i < 8; i++) pv[i] = ((const floatx4*)src)[i];
            if (part == 0) hc = coli[ge];
        }
        LGKM0();   // own-wave staging landed; no barrier
        half8 a[4];
#pragma unroll
        for (int kb = 0; kb < 4; kb++)
            a[kb] = *(const half8*)&sIn[row][kb * 32 + koff];
#pragma unroll
        for (int nt = 0; nt < 8; nt++) {
            floatx4 acc = {0.f, 0.f, 0.f, 0.f};
            const int c = nt * 16 + lm;
#pragma unroll
            for (int kb = 0; kb < 4; kb++) {
                half8 b = *(const half8*)&sW[c][kb * 32 + koff];
                acc = MFMA16(a[kb], b, acc);
            }
            sAcc[nt]  += acc[0] + acc[1] + acc[2] + acc[3];
            ssAcc[nt] += acc[0]*acc[0] + acc[1]*acc[1] + acc[2]*acc[2] + acc[3]*acc[3];
        }
    }
#pragma unroll
    for (int nt = 0; nt < 8; nt++) {
        float s  = col_reduce16(sAcc[nt]);
        float ss = col_reduce16(ssAcc[nt]);
        if (q == 0) {
            int c = nt * 16 + lm;
            int slot = (blockIdx.x * 8 + wv) & 15;
            unsafeAtomicAdd(&gsum[slot * 128 + c], s);
            unsafeAtomicAdd(&gsq[slot * 128 + c], ss);
        }
    }
}

// ------------------------------------------------------------ k_finalize ----
__global__ void k_finalize(const float* __restrict__ sums, const float* __restrict__ sqs,
                           const float* __restrict__ gamma, const float* __restrict__ beta,
                           float* __restrict__ scale, float* __restrict__ shift, float count) {
    int i = threadIdx.x;   // 128
    float s = 0.f, ssq = 0.f;
    for (int j = 0; j < 16; j++) { s += sums[j * 128 + i]; ssq += sqs[j * 128 + i]; }
    float mu = s / count;
    float var = ssq / count - mu * mu;      // biased, matches torch/jax ref
    float sc = gamma[i] * rsqrtf(var + 1e-5f);
    scale[i] = sc;
    shift[i] = beta[i] - mu * sc;
}

// ------------------------------------------------------------ k_edge_mlp ----
// Pass 2 on SORTED edges, BARRIER-FREE: wave-private staging, GEMM1, BN+ReLU
// into a ROW-MAJOR wave-private scratch (paired half2 writes; b128 row reads
// directly form GEMM2 A-frags), GEMM2(+b2a), segmented-scan scatter with
// tail-only pk-f16 atomics. Single LDS buffer; only lgkmcnt waits in-loop.
__global__ __launch_bounds__(512, 2) void k_edge_mlp(
    const float* __restrict__ x, const int2* __restrict__ pairs,
    const float* __restrict__ ea, const _Float16* __restrict__ w1t, const _Float16* __restrict__ w2t,
    const float* __restrict__ scale, const float* __restrict__ shift, const float* __restrict__ b2a,
    __half* __restrict__ agg, int nTiles) {
    __shared__ _Float16 sW1[128][136];
    __shared__ _Float16 sW2[128][136];
    __shared__ _Float16 sIn[128][136];   // staging, then row-major h_bn
    const int tid = threadIdx.x, lane = tid & 63, wv = tid >> 6;
    const int lm = lane & 15, q = lane >> 4, koff = q * 8;
    const int G = gridDim.x;
    const int e = tid >> 2, part = tid & 3;
    const int row = wv * 16 + lm;       // A-frag row (wave-private)
    const int m0 = wv * 16 + q * 4;     // D-frag rows m0..m0+3 (wave-private)

    {   // stage both weight matrices once
        int n = tid >> 2, seg = (tid & 3) * 32;
        const half8* s1 = (const half8*)(w1t + n * 128 + seg);
        half8* d1 = (half8*)&sW1[n][seg];
        d1[0] = s1[0]; d1[1] = s1[1]; d1[2] = s1[2]; d1[3] = s1[3];
        const half8* s2 = (const half8*)(w2t + n * 128 + seg);
        half8* d2 = (half8*)&sW2[n][seg];
        d2[0] = s2[0]; d2[1] = s2[1]; d2[2] = s2[2]; d2[3] = s2[3];
    }
    // per-lane BN consts for cols nt*16+lm (tile-invariant -> registers)
    float scl[8], shf[8], b2[8];
#pragma unroll
    for (int nt = 0; nt < 8; nt++) {
        scl[nt] = scale[nt * 16 + lm];
        shf[nt] = shift[nt * 16 + lm];
        b2[nt]  = b2a[nt * 16 + lm];
    }
    __syncthreads();   // weights visible; the only block-wide barrier

    int t = blockIdx.x;
    floatx4 pv[8]; int mc[4];
    {   // prologue: tile t input + dest cols
        long ge = (long)t * 128 + e;
        int2 pr = pairs[ge];
        const float* src = (part < 2) ? x + (long)(pr.y & 0xFFFF) * 64 + part * 32
                                      : ea + (long)pr.x * 64 + (part - 2) * 32;
#pragma unroll
        for (int i = 0; i < 8; i++) pv[i] = ((const floatx4*)src)[i];
#pragma unroll
        for (int r = 0; r < 4; r++)
            mc[r] = (int)(((unsigned)pairs[(long)t * 128 + m0 + r].y) >> 16);
    }
    for (; t < nTiles; t += G) {
        {   // stage tile rows (wave-private), f32->f16
            _Float16* dst = &sIn[e][part * 32];
#pragma unroll
            for (int i = 0; i < 8; i++) {
                half4h h = {(_Float16)pv[i][0], (_Float16)pv[i][1],
                            (_Float16)pv[i][2], (_Float16)pv[i][3]};
                *(half4h*)(dst + i * 4) = h;
            }
        }
        int myCol[4] = {mc[0], mc[1], mc[2], mc[3]};
        // run-boundary flags (stripe = this wave's 16 rows; cross-stripe runs
        // stay correct via atomics). Neighbors via intra-wave shuffles.
        int cp = __shfl(myCol[3], (lane - 16) & 63, 64);
        int cn = __shfl(myCol[0], (lane + 16) & 63, 64);
        const bool h0 = (q == 0) || (myCol[0] != cp);
        const bool h1 = myCol[1] != myCol[0];
        const bool h2 = myCol[2] != myCol[1];
        const bool h3 = myCol[3] != myCol[2];
        const bool t0 = h1, t1 = h2, t2 = h3;
        const bool t3 = (q == 3) || (myCol[3] != cn);
        const bool c0m = !h0, c1m = c0m && !h1, c2m = c1m && !h2, c3m = c2m && !h3;
        const int F0 = (h0 | h1 | h2 | h3) ? 1 : 0;
        int Fp1 = __shfl(F0, (lane - 16) & 63, 64);
        const bool add1 = (q >= 1) && !F0;
        const int F1 = (F0 || ((q >= 1) && Fp1)) ? 1 : 0;
        const bool add2 = (q >= 2) && !F1;
        const bool useC = (q >= 1) && !h0;

        int tn = t + G; bool hasNext = tn < nTiles;
        if (hasNext) {   // prefetch next tile (overlaps both GEMMs; vmcnt only)
            long ge = (long)tn * 128 + e;
            int2 pr = pairs[ge];
            const float* src = (part < 2) ? x + (long)(pr.y & 0xFFFF) * 64 + part * 32
                                          : ea + (long)pr.x * 64 + (part - 2) * 32;
#pragma unroll
            for (int i = 0; i < 8; i++) pv[i] = ((const floatx4*)src)[i];
#pragma unroll
            for (int r = 0; r < 4; r++)
                mc[r] = (int)(((unsigned)pairs[(long)tn * 128 + m0 + r].y) >> 16);
        }
        LGKM0();   // own-wave staging landed
        half8 a[4];
#pragma unroll
        for (int kb = 0; kb < 4; kb++)
            a[kb] = *(const half8*)&sIn[row][kb * 32 + koff];
        // GEMM1
        floatx4 acc1[8];
#pragma unroll
        for (int nt = 0; nt < 8; nt++) {
            floatx4 acc = {0.f, 0.f, 0.f, 0.f};
            const int c = nt * 16 + lm;
#pragma unroll
            for (int kb = 0; kb < 4; kb++) {
                half8 b = *(const half8*)&sW1[c][kb * 32 + koff];
                acc = MFMA16(a[kb], b, acc);
            }
            acc1[nt] = acc;
        }
        // BN+ReLU -> ROW-MAJOR h_bn into sIn (wave rows already consumed).
        // Pair adjacent cols (lm even/odd) via shfl_xor -> half2 writes.
#pragma unroll
        for (int nt = 0; nt < 8; nt++) {
#pragma unroll
            for (int r = 0; r < 4; r++) {
                float h = fmaxf(acc1[nt][r] * scl[nt] + shf[nt], 0.f);
                float g = __shfl_xor(h, 1, 64);
                if (!(lane & 1)) {
                    half2h pr2 = {(_Float16)h, (_Float16)g};
                    *(half2h*)&sIn[m0 + r][nt * 16 + lm] = pr2;
                }
            }
        }
        LGKM0();   // own-wave h_bn rows landed
        // GEMM2 A-frags are just b128 row reads (layout matches MFMA A)
        half8 a2[4];
#pragma unroll
        for (int kb = 0; kb < 4; kb++)
            a2[kb] = *(const half8*)&sIn[row][kb * 32 + koff];
        // GEMM2
#pragma unroll
        for (int nt = 0; nt < 8; nt++) {
            floatx4 acc = {0.f, 0.f, 0.f, 0.f};
            const int c = nt * 16 + lm;
#pragma unroll
            for (int kb = 0; kb < 4; kb++) {
                half8 b = *(const half8*)&sW2[c][kb * 32 + koff];
                acc = MFMA16(a2[kb], b, acc);
            }
            acc1[nt] = acc;   // reuse regs
        }
        // segmented-scan scatter: collapse equal-col runs, atomics at tails
#pragma unroll
        for (int nt = 0; nt < 8; nt++) {
            const int c = nt * 16 + lm;
            const int c0 = c & ~1;
            float bb = b2[nt];
            float v0 = acc1[nt][0] + bb, v1 = acc1[nt][1] + bb;
            float v2 = acc1[nt][2] + bb, v3 = acc1[nt][3] + bb;
            // in-lane segmented inclusive sums over rows m0..m0+3
            float s0 = v0;
            float s1 = h1 ? v1 : (s0 + v1);
            float s2 = h2 ? v2 : (s1 + v2);
            float s3 = h3 ? v3 : (s2 + v3);
            // cross-q segmented scan of trailing-run sums (Hillis-Steele)
            float S = s3;
            float Sp = __shfl(S, (lane - 16) & 63, 64);
            if (add1) S += Sp;
            float Sq = __shfl(S, (lane - 32) & 63, 64);
            if (add2) S += Sq;
            float Cc = __shfl(S, (lane - 16) & 63, 64);
            float C = useC ? Cc : 0.f;
            float f0 = c0m ? (s0 + C) : s0;
            float f1 = c1m ? (s1 + C) : s1;
            float f2 = c2m ? (s2 + C) : s2;
            float f3 = c3m ? (s3 + C) : s3;
            // half2 pairing across adjacent cols (lanes lm, lm^1)
            float g0 = __shfl_xor(f0, 1, 64), g1 = __shfl_xor(f1, 1, 64);
            float g2 = __shfl_xor(f2, 1, 64), g3 = __shfl_xor(f3, 1, 64);
            if ((lane & 1) == 0) {
                if (t0) unsafeAtomicAdd((__half2*)&agg[(size_t)myCol[0] * 128 + c0], __floats2half2_rn(f0, g0));
                if (t1) unsafeAtomicAdd((__half2*)&agg[(size_t)myCol[1] * 128 + c0], __floats2half2_rn(f1, g1));
            } else {
                if (t2) unsafeAtomicAdd((__half2*)&agg[(size_t)myCol[2] * 128 + c0], __floats2half2_rn(g2, f2));
                if (t3) unsafeAtomicAdd((__half2*)&agg[(size_t)myCol[3] * 128 + c0], __floats2half2_rn(g3, f3));
            }
        }
        // no barrier: next iteration's staging is wave-private; atomics fly
    }
}

// -------------------------------------------------------------- k_node_a ----
// h3 = concat(x, agg_f16) @ W1b (K=192); store h3 fp32 + BN stats.
__global__ __launch_bounds__(512, 2) void k_node_a(
    const float* __restrict__ x, const __half* __restrict__ agg,
    const _Float16* __restrict__ w1bt, float* __restrict__ h3,
    float* __restrict__ gsum, float* __restrict__ gsq, int N) {
    __shared__ _Float16 sIn[128][200];   // 192 + 8 pad
    __shared__ _Float16 sW[128][200];
    __shared__ float sSum[128], sSq[128];
    const int tid = threadIdx.x, lane = tid & 63, wv = tid >> 6;
    const long e0 = (long)blockIdx.x * 128;

    {   // stage W1b^T: each row 192 halves by 4 threads x 48 halves
        int n = tid >> 2, seg = (tid & 3) * 48;
        const half8* src = (const half8*)(w1bt + n * 192 + seg);
        half8* dst = (half8*)&sW[n][seg];
        dst[0] = src[0]; dst[1] = src[1]; dst[2] = src[2];
        dst[3] = src[3]; dst[4] = src[4]; dst[5] = src[5];
    }
    if (tid < 128) { sSum[tid] = 0.f; sSq[tid] = 0.f; }
    {
        int m = tid >> 2, seg = tid & 3;
        long gm = e0 + m;
        bool valid = gm < N;
        const float* srcx = x + gm * 64 + seg * 16;
        _Float16* dstx = &sIn[m][seg * 16];
#pragma unroll
        for (int i = 0; i < 4; i++) {
            floatx4 v = {0.f, 0.f, 0.f, 0.f};
            if (valid) v = ((const floatx4*)srcx)[i];
            half4h h = {(_Float16)v[0], (_Float16)v[1], (_Float16)v[2], (_Float16)v[3]};
            *(half4h*)(dstx + i * 4) = h;
        }
        const _Float16* srca = (const _Float16*)agg + gm * 128 + seg * 32;
        _Float16* dsta = &sIn[m][64 + seg * 32];
#pragma unroll
        for (int i = 0; i < 4; i++) {
            half8 v = {0, 0, 0, 0, 0, 0, 0, 0};
            if (valid) v = ((const half8*)srca)[i];
            *(half8*)(dsta + i * 8) = v;
        }
    }
    __syncthreads();

    const int lm = lane & 15, q = lane >> 4, koff = q * 8;
    half8 a[6];
#pragma unroll
    for (int kb = 0; kb < 6; kb++)
        a[kb] = *(const half8*)&sIn[wv * 16 + lm][kb * 32 + koff];
#pragma unroll
    for (int nt = 0; nt < 8; nt++) {
        floatx4 acc = {0.f, 0.f, 0.f, 0.f};
        const int c = nt * 16 + lm;
#pragma unroll
        for (int kb = 0; kb < 6; kb++) {
            half8 b = *(const half8*)&sW[c][kb * 32 + koff];
            acc = MFMA16(a[kb], b, acc);
        }
        float s  = acc[0] + acc[1] + acc[2] + acc[3];
        float ss = acc[0]*acc[0] + acc[1]*acc[1] + acc[2]*acc[2] + acc[3]*acc[3];
        s = col_reduce16(s); ss = col_reduce16(ss);
        if (q == 0) { atomicAdd(&sSum[c], s); atomicAdd(&sSq[c], ss); }
#pragma unroll
        for (int r = 0; r < 4; r++) {
            int m2 = wv * 16 + q * 4 + r;
            long gm2 = e0 + m2;
            if (gm2 < N) h3[gm2 * 128 + c] = acc[r];
        }
    }
    __syncthreads();
    if (tid < 128) {
        int slot = blockIdx.x & 15;
        unsafeAtomicAdd(&gsum[slot * 128 + tid], sSum[tid]);
        unsafeAtomicAdd(&gsq[slot * 128 + tid], sSq[tid]);
    }
}

// -------------------------------------------------------------- k_node_b ----
__global__ __launch_bounds__(512, 2) void k_node_b(
    const float* __restrict__ h3, const _Float16* __restrict__ w2bt,
    const float* __restrict__ scale, const float* __restrict__ shift,
    const float* __restrict__ b2b, float* __restrict__ out, int N) {
    __shared__ _Float16 sH[128][136];
    __shared__ _Float16 sW[64][136];
    const int tid = threadIdx.x, lane = tid & 63, wv = tid >> 6;
    const long e0 = (long)blockIdx.x * 128;

    {
        int n = tid >> 3, seg = (tid & 7) * 16;
        const half8* src = (const half8*)(w2bt + n * 128 + seg);
        half8* dst = (half8*)&sW[n][seg];
        dst[0] = src[0]; dst[1] = src[1];
    }
    {   // stage h3 with BN+ReLU applied
        int m = tid >> 2, seg = (tid & 3) * 32;
        long gm = e0 + m;
        bool valid = gm < N;
        const float* src = h3 + gm * 128 + seg;
        _Float16* dst = &sH[m][seg];
#pragma unroll
        for (int i = 0; i < 8; i++) {
            floatx4 v = {0.f, 0.f, 0.f, 0.f};
            if (valid) v = ((const floatx4*)src)[i];
            floatx4 sc = ((const floatx4*)(scale + seg))[i];
            floatx4 sh = ((const floatx4*)(shift + seg))[i];
            half4h h;
#pragma unroll
            for (int j = 0; j < 4; j++)
                h[j] = (_Float16)fmaxf(v[j] * sc[j] + sh[j], 0.f);
            *(half4h*)(dst + i * 4) = h;
        }
    }
    __syncthreads();

    const int lm = lane & 15, q = lane >> 4, koff = q * 8;
    half8 a[4];
#pragma unroll
    for (int kb = 0; kb < 4; kb++)
        a[kb] = *(const half8*)&sH[wv * 16 + lm][kb * 32 + koff];
#pragma unroll
    for (int nt = 0; nt < 4; nt++) {
        floatx4 acc = {0.f, 0.f, 0.f, 0.f};
        const int c = nt * 16 + lm;
#pragma unroll
        for (int kb = 0; kb < 4; kb++) {
            half8 b = *(const half8*)&sW[c][kb * 32 + koff];
            acc = MFMA16(a[kb], b, acc);
        }
        float bb = b2b[c];
#pragma unroll
        for (int r = 0; r < 4; r++) {
            int m2 = wv * 16 + q * 4 + r;
            long gm2 = e0 + m2;
            if (gm2 < N) out[gm2 * 64 + c] = acc[r] + bb;
        }
    }
}

// --------------------------------------------------------------- launch -----
extern "C" void kernel_launch(void* const* d_in, const int* in_sizes, int n_in,
                              void* d_out, int out_size, void* d_ws, size_t ws_size,
                              hipStream_t stream) {
    const float* x    = (const float*)d_in[0];
    const int*   eidx = (const int*)d_in[1];
    const float* ea   = (const float*)d_in[2];
    const float* W1a  = (const float*)d_in[5];
    const float* g1a  = (const float*)d_in[7];
    const float* be1a = (const float*)d_in[8];
    const float* W2a  = (const float*)d_in[9];
    const float* b2a  = (const float*)d_in[10];
    const float* W1b  = (const float*)d_in[11];
    const float* g1b  = (const float*)d_in[13];
    const float* be1b = (const float*)d_in[14];
    const float* W2b  = (const float*)d_in[15];
    const float* b2b  = (const float*)d_in[16];
    const int N = in_sizes[0] / 64;
    const int E = in_sizes[2] / 64;
    const int* rowi = eidx;
    const int* coli = eidx + E;

    // workspace layout (~46 MB)
    float* ws   = (float*)d_ws;
    __half* agg = (__half*)ws;                    // N*128 halves (= N*64 floats)
    float* h3   = ws + (size_t)N * 64;            // N*128 floats
    float* st   = h3 + (size_t)N * 128;           // stats block
    float* sumE = st,        * sqE = st + 2048;   // 16 slots x 128
    float* sumN = st + 4096, * sqN = st + 6144;
    float* scE  = st + 8192, * shE = st + 8320;
    float* scN  = st + 8448, * shN = st + 8576;
    _Float16* wh   = (_Float16*)(st + 8704);      // 16B-aligned
    _Float16* w1at = wh;
    _Float16* w2at = wh + 16384;
    _Float16* w1bt = wh + 32768;
    _Float16* w2bt = wh + 57344;
    int* cnt  = (int*)(wh + 65536);               // N
    int* cur  = cnt + N;                          // N
    int2* pairs = (int2*)(cur + N);               // E x {eid, col<<16|row}

    hipMemsetAsync(agg, 0, (size_t)N * 128 * sizeof(__half), stream);
    hipMemsetAsync(st, 0, 8192 * sizeof(float), stream);
    hipMemsetAsync(cnt, 0, (size_t)N * sizeof(int), stream);
    k_prep<<<256, 256, 0, stream>>>(W1a, W2a, W1b, W2b, w1at, w2at, w1bt, w2bt);

    int nTilesE = E / 128;                        // E = 800000 -> 6250 exact
    int nbl = (N + 127) / 128;
    int nbE = (E + 511) / 512;
    // pass 1 (stats + fused dest histogram)
    k_edge_stats<<<512, 512, 0, stream>>>(x, rowi, coli, ea, w1at, sumE, sqE, cnt, nTilesE);
    // sort finish: scan + scatter(+edge-BN finalize)
    k_scan<<<1, 1024, 0, stream>>>(cnt, cur, N);
    k_scatter_fin<<<nbE, 512, 0, stream>>>(rowi, coli, cur, pairs, sumE, sqE, g1a, be1a,
                                           scE, shE, (float)E, E);
    // pass 2 (BN+GEMM2+reduced scatter)
    k_edge_mlp<<<256, 512, 0, stream>>>(x, pairs, ea, w1at, w2at, scE, shE, b2a, agg, nTilesE);
    k_node_a<<<nbl, 512, 0, stream>>>(x, agg, w1bt, h3, sumN, sqN, N);
    k_finalize<<<1, 128, 0, stream>>>(sumN, sqN, g1b, be1b, scN, shN, (float)N);
    k_node_b<<<nbl, 512, 0, stream>>>(h3, w2bt, scN, shN, b2b, (float*)d_out, N);
}